// Round 1
// baseline (721.742 us; speedup 1.0000x reference)
//
#include <hip/hip_runtime.h>
#include <stdint.h>

#define NF 64
#define ND 128
#define NPAIR 2016      // 64*63/2
#define NB 2            // batches per workgroup
#define THREADS 256

typedef __attribute__((ext_vector_type(4))) float  f32x4;
typedef __attribute__((ext_vector_type(16))) float f32x16;
typedef __attribute__((ext_vector_type(4))) short  s16x4;
typedef __attribute__((ext_vector_type(8))) short  s16x8;

// fp32 -> bf16 round-to-nearest-even (inputs are finite normals; no NaN path needed)
__device__ __forceinline__ short f2bf(float v) {
    union { float f; unsigned u; } c; c.f = v;
    unsigned u = c.u;
    u += 0x7fffu + ((u >> 16) & 1u);
    return (short)(u >> 16);
}

// LDS layout per batch: 64 rows x 16 k-chunks, each chunk = 8 bf16 = 16 B.
// chunk index = row*16 + (kc ^ (row & 15))   (XOR swizzle: bank-spread for both
// staging writes (kc-fastest) and fragment reads (row-fastest)).
__global__ __launch_bounds__(THREADS, 4) void dotint_kernel(
    const float* __restrict__ x, float* __restrict__ out)
{
    __shared__ short lds[NB * NF * ND];   // 2 * 8192 bf16 = 32 KiB

    const int t  = threadIdx.x;
    const long long b0 = (long long)blockIdx.x * NB;

    // ---------------- stage: coalesced fp32 -> bf16 LDS ----------------
    // flat float4 index f in [0, NB*2048); global float4 = b0*2048 + f
    const f32x4* xg = (const f32x4*)x + b0 * (NF * ND / 4);
    #pragma unroll
    for (int o = 0; o < 2; ++o) {
        f32x4 v[8];
        #pragma unroll
        for (int i = 0; i < 8; ++i) {
            const int f = t + THREADS * (o * 8 + i);
            v[i] = xg[f];
        }
        #pragma unroll
        for (int i = 0; i < 8; ++i) {
            const int f      = t + THREADS * (o * 8 + i);
            const int bl     = f >> 11;          // local batch
            const int within = f & 2047;
            const int row    = within >> 5;      // 32 float4 per row
            const int k4     = within & 31;
            const int kc     = k4 >> 1;
            const int half   = k4 & 1;
            const int chunk  = row * 16 + (kc ^ (row & 15));
            s16x4 p;
            p[0] = f2bf(v[i][0]);
            p[1] = f2bf(v[i][1]);
            p[2] = f2bf(v[i][2]);
            p[3] = f2bf(v[i][3]);
            *(s16x4*)&lds[bl * (NF * ND) + chunk * 8 + half * 4] = p;
        }
    }
    __syncthreads();

    // ---------------- compute: 3 gram tiles per batch via MFMA ----------------
    const int lane = t & 63;
    const int wave = t >> 6;
    const int lr   = lane & 31;   // row-in-tile for A/B frag, col for C
    const int lh   = lane >> 5;   // k-half selector

    // tasks: bl in {0,1} x tile in {0:(0,0), 1:(0,1), 2:(1,1)}; 6 tasks over 4 waves
    for (int task = wave; task < NB * 3; task += 4) {
        const int bl   = task / 3;
        const int tile = task % 3;
        const int I = tile >> 1;         // 0,0,1
        const int J = (tile + 1) >> 1;   // 0,1,1
        const short* base = &lds[bl * (NF * ND)];

        f32x16 acc;
        #pragma unroll
        for (int r = 0; r < 16; ++r) acc[r] = 0.0f;

        #pragma unroll
        for (int kb = 0; kb < 8; ++kb) {
            const int sw = (kb * 2 + lh) ^ (lr & 15);  // (row&15)==(lr&15): 32|I*32
            s16x8 a = *(const s16x8*)&base[((I * 32 + lr) * 16 + sw) * 8];
            s16x8 b = (I == J) ? a
                    : *(const s16x8*)&base[((J * 32 + lr) * 16 + sw) * 8];
            acc = __builtin_amdgcn_mfma_f32_32x32x16_bf16(a, b, acc, 0, 0, 0);
        }

        // epilogue: C layout col=lane&31, row=(reg&3)+8*(reg>>2)+4*(lane>>5)
        const long long ob = (b0 + bl) * (long long)NPAIR;
        #pragma unroll
        for (int r = 0; r < 16; ++r) {
            const int rowInTile = (r & 3) + 8 * (r >> 2) + 4 * lh;
            const int i = I * 32 + rowInTile;
            const int j = J * 32 + lr;
            if (j > i) {
                const int tri = i * (127 - i) / 2 + (j - i - 1);
                out[ob + tri] = acc[r];
            }
        }
    }
}

extern "C" void kernel_launch(void* const* d_in, const int* in_sizes, int n_in,
                              void* d_out, int out_size, void* d_ws, size_t ws_size,
                              hipStream_t stream) {
    const float* x = (const float*)d_in[0];
    float* out = (float*)d_out;
    const int B = in_sizes[0] / (NF * ND);   // 16384
    dim3 grid(B / NB), block(THREADS);
    hipLaunchKernelGGL(dotint_kernel, grid, block, 0, stream, x, out);
}

// Round 2
// 705.999 us; speedup vs baseline: 1.0223x; 1.0223x over previous
//
#include <hip/hip_runtime.h>
#include <stdint.h>

#define NF 64
#define ND 128
#define NPAIR 2016      // 64*63/2
#define THREADS 256

typedef __attribute__((ext_vector_type(4))) float  f32x4;
typedef __attribute__((ext_vector_type(16))) float f32x16;
typedef __attribute__((ext_vector_type(4))) short  s16x4;
typedef __attribute__((ext_vector_type(8))) short  s16x8;

// fp32 -> bf16 round-to-nearest-even
__device__ __forceinline__ short f2bf(float v) {
    union { float f; unsigned u; } c; c.f = v;
    unsigned u = c.u;
    u += 0x7fffu + ((u >> 16) & 1u);
    return (short)(u >> 16);
}

// One batch per WG. LDS: 64 rows x 16 k-chunks (8 bf16 = 16 B each),
// chunk = row*16 + (kc ^ (row&15)) — XOR swizzle keeps both staging writes
// and fragment reads bank-uniform.
// 16 KiB LDS + launch_bounds(256,8) -> target 8 WGs/CU (32 waves/CU) for
// cross-WG load/compute overlap.
__global__ __launch_bounds__(THREADS, 8) void dotint_kernel(
    const float* __restrict__ x, float* __restrict__ out)
{
    __shared__ short lds[NF * ND];   // 8192 bf16 = 16 KiB

    const int t = threadIdx.x;
    const long long b = blockIdx.x;

    // ---------------- stage: coalesced fp32 -> bf16 LDS ----------------
    // 2048 float4 per batch; 2 rounds x 4 float4/thread (keeps live VGPRs low)
    const f32x4* xg = (const f32x4*)x + b * (NF * ND / 4);
    #pragma unroll
    for (int o = 0; o < 2; ++o) {
        f32x4 v[4];
        #pragma unroll
        for (int i = 0; i < 4; ++i)
            v[i] = xg[t + THREADS * (o * 4 + i)];
        #pragma unroll
        for (int i = 0; i < 4; ++i) {
            const int f     = t + THREADS * (o * 4 + i);
            const int row   = f >> 5;            // 32 float4 per row
            const int k4    = f & 31;
            const int kc    = k4 >> 1;
            const int half  = k4 & 1;
            const int chunk = row * 16 + (kc ^ (row & 15));
            s16x4 p;
            p[0] = f2bf(v[i][0]);
            p[1] = f2bf(v[i][1]);
            p[2] = f2bf(v[i][2]);
            p[3] = f2bf(v[i][3]);
            *(s16x4*)&lds[chunk * 8 + half * 4] = p;
        }
    }
    __syncthreads();

    // ---------------- compute: wave w handles gram tile w ----------------
    // tiles: 0:(0,0) 1:(0,1) 2:(1,1); wave 3 idle (stage-only helper)
    const int wave = t >> 6;
    if (wave < 3) {
        const int lane = t & 63;
        const int lr   = lane & 31;   // row-in-tile for A/B frag, col for C
        const int lh   = lane >> 5;   // k-half selector
        const int I = wave >> 1;          // 0,0,1
        const int J = (wave + 1) >> 1;    // 0,1,1

        f32x16 acc;
        #pragma unroll
        for (int r = 0; r < 16; ++r) acc[r] = 0.0f;

        #pragma unroll
        for (int kb = 0; kb < 8; ++kb) {
            const int sw = (kb * 2 + lh) ^ (lr & 15);  // (row&15)==(lr&15)
            s16x8 a = *(const s16x8*)&lds[((I * 32 + lr) * 16 + sw) * 8];
            s16x8 bb = (I == J) ? a
                     : *(const s16x8*)&lds[((J * 32 + lr) * 16 + sw) * 8];
            acc = __builtin_amdgcn_mfma_f32_32x32x16_bf16(a, bb, acc, 0, 0, 0);
        }

        // epilogue: C layout col=lane&31, row=(reg&3)+8*(reg>>2)+4*(lane>>5)
        const long long ob = b * (long long)NPAIR;
        #pragma unroll
        for (int r = 0; r < 16; ++r) {
            const int rowInTile = (r & 3) + 8 * (r >> 2) + 4 * lh;
            const int i = I * 32 + rowInTile;
            const int j = J * 32 + lr;
            if (j > i) {
                const int tri = i * (127 - i) / 2 + (j - i - 1);
                out[ob + tri] = acc[r];
            }
        }
    }
}

extern "C" void kernel_launch(void* const* d_in, const int* in_sizes, int n_in,
                              void* d_out, int out_size, void* d_ws, size_t ws_size,
                              hipStream_t stream) {
    const float* x = (const float*)d_in[0];
    float* out = (float*)d_out;
    const int B = in_sizes[0] / (NF * ND);   // 16384
    dim3 grid(B), block(THREADS);
    hipLaunchKernelGGL(dotint_kernel, grid, block, 0, stream, x, out);
}